// Round 3
// baseline (250.876 us; speedup 1.0000x reference)
//
#include <hip/hip_runtime.h>

// TSM (temporal shift): x (128,96,56,56) f32 viewed as (16,8,96,56,56).
//   c in [0,32):  out[b,t] = x[b,t+1]  (zero at t=7)
//   c in [32,64): out[b,t] = x[b,t-1]  (zero at t=0)
//   c in [64,96): out[b,t] = x[b,t]
// R3: 4 planes per block (grid 3072, plane-stride 3072). 3072%96==0 and
// 3072/96==32 frames == 4 whole batches, so all 4 planes in a block share
// (c,t): shift/zero logic stays block-uniform. All ~12-16 loads issue before
// any store -> ~4x the in-flight memory ops per wave vs R2.

#define C_TOT   96
#define FOLD    32
#define NFRAME  8
#define HW4     784       // 56*56/4 float4 per plane
#define NPLANES 12288     // 128*96
#define PPB     4         // planes per block
#define GRID    (NPLANES / PPB)   // 3072

typedef float v4f __attribute__((ext_vector_type(4)));

__global__ __launch_bounds__(256) void tsm_kernel(const v4f* __restrict__ in,
                                                  v4f* __restrict__ out) {
    const int p = blockIdx.x;                  // base plane; block handles p + k*GRID
    const int c = p % C_TOT;
    const int t = (p / C_TOT) % NFRAME;        // same (c,t) for all 4 planes

    int  delta = 0;                            // block-uniform scalars
    bool zero  = false;
    if (c < FOLD)          { delta =  C_TOT; zero = (t == NFRAME - 1); }
    else if (c < 2 * FOLD) { delta = -C_TOT; zero = (t == 0); }

    const int  j    = threadIdx.x;             // 784 = 3*256 + 16
    const bool tail = (j < HW4 - 768);

    long base[PPB];
    #pragma unroll
    for (int k = 0; k < PPB; ++k) base[k] = ((long)p + (long)k * GRID) * HW4;

    if (zero) {
        const v4f z = (v4f){0.f, 0.f, 0.f, 0.f};
        #pragma unroll
        for (int k = 0; k < PPB; ++k) {
            v4f* o = out + base[k];
            __builtin_nontemporal_store(z, &o[j]);
            __builtin_nontemporal_store(z, &o[j + 256]);
            __builtin_nontemporal_store(z, &o[j + 512]);
            if (tail) __builtin_nontemporal_store(z, &o[j + 768]);
        }
    } else {
        const long soff = (long)delta * HW4;
        v4f r[PPB][3];
        v4f rt[PPB];
        #pragma unroll
        for (int k = 0; k < PPB; ++k) {        // all loads first: max MLP
            const v4f* s = in + base[k] + soff;
            r[k][0] = __builtin_nontemporal_load(&s[j]);
            r[k][1] = __builtin_nontemporal_load(&s[j + 256]);
            r[k][2] = __builtin_nontemporal_load(&s[j + 512]);
            if (tail) rt[k] = __builtin_nontemporal_load(&s[j + 768]);
        }
        #pragma unroll
        for (int k = 0; k < PPB; ++k) {        // then all stores
            v4f* o = out + base[k];
            __builtin_nontemporal_store(r[k][0], &o[j]);
            __builtin_nontemporal_store(r[k][1], &o[j + 256]);
            __builtin_nontemporal_store(r[k][2], &o[j + 512]);
            if (tail) __builtin_nontemporal_store(rt[k], &o[j + 768]);
        }
    }
}

extern "C" void kernel_launch(void* const* d_in, const int* in_sizes, int n_in,
                              void* d_out, int out_size, void* d_ws, size_t ws_size,
                              hipStream_t stream) {
    const v4f* x   = (const v4f*)d_in[0];
    v4f*       out = (v4f*)d_out;
    tsm_kernel<<<GRID, 256, 0, stream>>>(x, out);
}